// Round 2
// baseline (544.726 us; speedup 1.0000x reference)
//
#include <hip/hip_runtime.h>
#include <hip/hip_bf16.h>
#include <stdint.h>

// ---------------------------------------------------------------------------
// QuantGRU: T=512, B=64, I=256, H=256. ACT scale 2^-7, W scale 2^-8.
// Everything is exact integer arithmetic except sigmoid/tanh (256-entry LUTs).
// ---------------------------------------------------------------------------

#define T_STEPS 512
#define BATCH   64
#define IDIM    256
#define HDIM    256
#define N3H     768   // 3*H

#if defined(__has_builtin)
#if __has_builtin(__builtin_amdgcn_sdot4)
#define DOT4(a,b,c) __builtin_amdgcn_sdot4((int)(a),(int)(b),(int)(c),false)
#endif
#endif
#ifndef DOT4
__device__ __forceinline__ int dot4_sw(uint32_t a, uint32_t b, int c){
  c += (int)(int8_t)(a)      * (int)(int8_t)(b);
  c += (int)(int8_t)(a>>8)   * (int)(int8_t)(b>>8);
  c += (int)(int8_t)(a>>16)  * (int)(int8_t)(b>>16);
  c += (int)(int8_t)(a>>24)  * (int)(int8_t)(b>>24);
  return c;
}
#define DOT4(a,b,c) dot4_sw((uint32_t)(a),(uint32_t)(b),(int)(c))
#endif

// round-to-nearest-even + clamp to int8 range (matches jnp.round + clip)
__device__ __forceinline__ int rneclamp(float v) {
  int q = (int)rintf(v);
  return min(127, max(-128, q));
}

__device__ __forceinline__ uint32_t packq4(float4 f, float sc) {
  uint32_t b0 = (uint32_t)(uint8_t)(int8_t)rneclamp(f.x * sc);
  uint32_t b1 = (uint32_t)(uint8_t)(int8_t)rneclamp(f.y * sc);
  uint32_t b2 = (uint32_t)(uint8_t)(int8_t)rneclamp(f.z * sc);
  uint32_t b3 = (uint32_t)(uint8_t)(int8_t)rneclamp(f.w * sc);
  return b0 | (b1 << 8) | (b2 << 16) | (b3 << 24);
}

// ---------------------------------------------------------------------------
// prep: quantize W (I x 3H) and R (H x 3H) to int8 COLUMN-MAJOR, biases to int8
// ---------------------------------------------------------------------------
__global__ void prep_kernel(const float* __restrict__ W, const float* __restrict__ R,
                            const float* __restrict__ bx, const float* __restrict__ br,
                            int8_t* __restrict__ Wq8cm, int8_t* __restrict__ Rq8cm,
                            int8_t* __restrict__ bx8, int8_t* __restrict__ br8) {
  const int NW = IDIM * N3H; // 196608
  int idx = blockIdx.x * 256 + threadIdx.x;
  if (idx < NW) {
    int k = idx / N3H, j = idx % N3H;
    Wq8cm[(size_t)j * IDIM + k] = (int8_t)rneclamp(W[idx] * 256.0f);
  } else if (idx < 2 * NW) {
    int i2 = idx - NW;
    int k = i2 / N3H, j = i2 % N3H;
    Rq8cm[(size_t)j * HDIM + k] = (int8_t)rneclamp(R[i2] * 256.0f);
  } else if (idx < 2 * NW + N3H) {
    int i2 = idx - 2 * NW;
    bx8[i2] = (int8_t)rneclamp(bx[i2] * 256.0f);
  } else if (idx < 2 * NW + 2 * N3H) {
    int i2 = idx - 2 * NW - N3H;
    br8[i2] = (int8_t)rneclamp(br[i2] * 256.0f);
  }
}

// ---------------------------------------------------------------------------
// gemm_wx: Wx_q[b][t][j] = clamp(rne( (fq(x) . Wq col j) / 256 ))  (int8)
// one block per t (64 rows), 768 threads = one per output column.
// ---------------------------------------------------------------------------
__global__ __launch_bounds__(768, 1) void gemm_wx_kernel(
    const float* __restrict__ x, const int8_t* __restrict__ Wq8cm,
    int8_t* __restrict__ WxQ8) {
  const int t = blockIdx.x;   // 0..511
  const int j = threadIdx.x;  // 0..767

  __shared__ uint4 xq4[64 * 16];   // 64 rows x 256 int8 = 16KB
  uint32_t* xq = (uint32_t*)xq4;

  // weights for column j: 256 int8 = 16 uint4 in VGPRs
  uint4 w[16];
  const uint4* wp = (const uint4*)(Wq8cm + (size_t)j * IDIM);
  #pragma unroll
  for (int kk = 0; kk < 16; ++kk) w[kk] = wp[kk];

  // stage + quantize x tile: rows m = t*64 .. t*64+63  (x[t][b][:], b=0..63)
  const float4* xg = (const float4*)(x) + (size_t)t * 4096;
  for (int i = j; i < 4096; i += 768) {
    float4 f = xg[i];
    xq[i] = packq4(f, 128.0f);
  }
  __syncthreads();

  for (int r = 0; r < 64; ++r) {
    int s = 0;
    #pragma unroll
    for (int kk = 0; kk < 16; ++kk) {
      uint4 hv = xq4[r * 16 + kk];
      s = DOT4(hv.x, w[kk].x, s);
      s = DOT4(hv.y, w[kk].y, s);
      s = DOT4(hv.z, w[kk].z, s);
      s = DOT4(hv.w, w[kk].w, s);
    }
    // value = s/2^15 ; fq(.,7): rne(s/256), clamp
    int q = rneclamp((float)s * (1.0f / 256.0f));
    // layout [b][t][j] for sequential streaming in the recurrence
    WxQ8[((size_t)r * T_STEPS + t) * N3H + j] = (int8_t)q;
  }
}

// ---------------------------------------------------------------------------
// gru_rec: one block per batch element; 768 threads.
//   phase A (768 thr): v = fq(fq(hq@Rq)+brq)  (int8 GEMV, K=256)
//   phase B (256 thr): gates via LUT, h update, output store
// ---------------------------------------------------------------------------
__global__ __launch_bounds__(768, 1) void gru_rec_kernel(
    const float* __restrict__ h0, const int8_t* __restrict__ Rq8cm,
    const int8_t* __restrict__ bx8, const int8_t* __restrict__ br8,
    const int8_t* __restrict__ WxQ8, float* __restrict__ out) {
  const int b = blockIdx.x;   // batch element
  const int j = threadIdx.x;  // 0..767

  __shared__ uint4 hq4[16];        // 256 int8 quantized h
  __shared__ int   v32[N3H];
  __shared__ int   wxs[N3H];
  __shared__ int8_t lutS[256];
  __shared__ int8_t lutT[256];

  // R column j in registers
  uint4 w[16];
  const uint4* wp = (const uint4*)(Rq8cm + (size_t)j * HDIM);
  #pragma unroll
  for (int kk = 0; kk < 16; ++kk) w[kk] = wp[kk];
  const int brj = (int)br8[j];

  // gate-thread persistent state
  float hf = 0.0f;
  int bzc = 0, brc = 0, bgc = 0;
  if (j < HDIM) {
    hf  = h0[b * HDIM + j];
    bzc = (int)bx8[j];
    brc = (int)bx8[j + HDIM];
    bgc = (int)bx8[j + 2 * HDIM];
    // LUTs: inputs are fq-clamped to k/128, k in [-128,127]
    double a = (double)(j - 128) / 128.0;
    lutS[j] = (int8_t)min(127, max(-128, (int)rint(128.0 / (1.0 + exp(-a)))));
    lutT[j] = (int8_t)min(127, max(-128, (int)rint(128.0 * tanh(a))));
    // initial hq = fq(h0,7) as int
    ((int8_t*)hq4)[j] = (int8_t)rneclamp(hf * 128.0f);
  }
  __syncthreads();

  const int8_t* wxp = WxQ8 + (size_t)b * T_STEPS * N3H + j;
  float* outp = out + (size_t)b * HDIM + (j < HDIM ? j : 0);

  for (int t = 0; t < T_STEPS; ++t) {
    // ---- phase A: issue Wx load early, GEMV hq @ Rq column j ----
    int wxb = (int)wxp[(size_t)t * N3H];
    int s = 0;
    #pragma unroll
    for (int kk = 0; kk < 16; ++kk) {
      uint4 hv = hq4[kk];
      s = DOT4(hv.x, w[kk].x, s);
      s = DOT4(hv.y, w[kk].y, s);
      s = DOT4(hv.z, w[kk].z, s);
      s = DOT4(hv.w, w[kk].w, s);
    }
    // Rh = fq(hq@Rq, 7): value s/2^15 -> rne(s/256) clamp
    int Rh = rneclamp((float)s * (1.0f / 256.0f));
    // v = fq(Rh + brq, 7) = rne((2*Rh + br)/2) clamp
    int v = rneclamp((float)(2 * Rh + brj) * 0.5f);
    v32[j] = v;
    wxs[j] = wxb;
    __syncthreads();

    // ---- phase B: gates (threads 0..255) ----
    if (j < HDIM) {
      int vz = v32[j], vr = v32[j + HDIM], vg = v32[j + 2 * HDIM];
      int wz = wxs[j], wr = wxs[j + HDIM], wg = wxs[j + 2 * HDIM];
      // az = fq(wz+bz+vz,7)*128 = rne((2wz + bz + 2vz)/2) clamp
      int az = rneclamp((float)(2 * wz + bzc + 2 * vz) * 0.5f);
      int zi = (int)lutS[az + 128];
      int ar = rneclamp((float)(2 * wr + brc + 2 * vr) * 0.5f);
      int ri = (int)lutS[ar + 128];
      // rRh = fq(r*vg,7): (ri/128)*(vg/128)*128 = ri*vg/128
      int rrh = rneclamp((float)(ri * vg) * (1.0f / 128.0f));
      int ag = rneclamp((float)(2 * wg + bgc + 2 * rrh) * 0.5f);
      int gi = (int)lutT[ag + 128];
      // old = fq(z*h,7): (zi/128)*hf*128 = zi*hf  (exact; hf is f32 value of h)
      int oldi = rneclamp((float)zi * hf);
      // new = fq((1-z)*g,7): ((128-zi)/128)*(gi/128)*128 = (128-zi)*gi/128
      int newi = rneclamp((float)((128 - zi) * gi) * (1.0f / 128.0f));
      int hi = oldi + newi;            // integer, units 1/128
      hf = (float)hi * (1.0f / 128.0f);
      outp[(size_t)t * BATCH * HDIM] = hf;   // out[t][b][c]
      // hq for next step: clamp(hi) since hi is already integer
      ((int8_t*)hq4)[j] = (int8_t)min(127, max(-128, hi));
    }
    __syncthreads();
  }
}

// ---------------------------------------------------------------------------
extern "C" void kernel_launch(void* const* d_in, const int* in_sizes, int n_in,
                              void* d_out, int out_size, void* d_ws, size_t ws_size,
                              hipStream_t stream) {
  const float* x  = (const float*)d_in[0];   // (T,B,I)
  const float* h0 = (const float*)d_in[1];   // (B,H)
  const float* W  = (const float*)d_in[2];   // (I,3H)
  const float* R  = (const float*)d_in[3];   // (H,3H)
  const float* bx = (const float*)d_in[4];   // (3H,)
  const float* br = (const float*)d_in[5];   // (3H,)
  float* out = (float*)d_out;                // (T,B,H)

  // workspace layout
  const size_t NW = (size_t)IDIM * N3H;          // 196608
  int8_t* Wq8cm = (int8_t*)d_ws;                 // 196608
  int8_t* Rq8cm = Wq8cm + NW;                    // 196608
  int8_t* bx8   = Rq8cm + NW;                    // 768
  int8_t* br8   = bx8 + N3H;                     // 768
  int8_t* WxQ8  = br8 + N3H;                     // 64*512*768 = 25165824

  // 1) quantize weights/biases
  {
    int total = (int)(2 * NW + 2 * N3H);
    int blocks = (total + 255) / 256;
    prep_kernel<<<blocks, 256, 0, stream>>>(W, R, bx, br, Wq8cm, Rq8cm, bx8, br8);
  }
  // 2) Wx GEMM (int8)
  gemm_wx_kernel<<<T_STEPS, 768, 0, stream>>>(x, Wq8cm, WxQ8);
  // 3) recurrence: one block per batch element
  gru_rec_kernel<<<BATCH, 768, 0, stream>>>(h0, Rq8cm, bx8, br8, WxQ8, out);
}

// Round 3
// 488.827 us; speedup vs baseline: 1.1144x; 1.1144x over previous
//
#include <hip/hip_runtime.h>
#include <hip/hip_bf16.h>
#include <stdint.h>

// ---------------------------------------------------------------------------
// QuantGRU: T=512, B=64, I=256, H=256. ACT scale 2^-7, W scale 2^-8.
// Exact integer arithmetic; sigmoid/tanh via 256-entry f64-built LUTs.
// Recurrence: h-broadcast via ds_read_b32 + v_readlane -> SGPR -> v_dot4
// (avoids the LDS wave-uniform b128 broadcast bottleneck: 2304 cyc/step).
// ---------------------------------------------------------------------------

#define T_STEPS 512
#define BATCH   64
#define IDIM    256
#define HDIM    256
#define N3H     768   // 3*H

#if defined(__has_builtin)
#if __has_builtin(__builtin_amdgcn_sdot4)
#define DOT4(a,b,c) __builtin_amdgcn_sdot4((int)(a),(int)(b),(int)(c),false)
#endif
#endif
#ifndef DOT4
__device__ __forceinline__ int dot4_sw(uint32_t a, uint32_t b, int c){
  c += (int)(int8_t)(a)      * (int)(int8_t)(b);
  c += (int)(int8_t)(a>>8)   * (int)(int8_t)(b>>8);
  c += (int)(int8_t)(a>>16)  * (int)(int8_t)(b>>16);
  c += (int)(int8_t)(a>>24)  * (int)(int8_t)(b>>24);
  return c;
}
#define DOT4(a,b,c) dot4_sw((uint32_t)(a),(uint32_t)(b),(int)(c))
#endif

// select dword component of a uint4 by compile-time constant (stays in VGPRs)
#define CHUNK(W,c) (((c)&3)==0 ? W[(c)>>2].x : ((c)&3)==1 ? W[(c)>>2].y : \
                    ((c)&3)==2 ? W[(c)>>2].z : W[(c)>>2].w)

// round-to-nearest-even + clamp to int8 range (matches jnp.round + clip)
__device__ __forceinline__ int rneclamp(float v) {
  int q = (int)rintf(v);
  return min(127, max(-128, q));
}

__device__ __forceinline__ uint32_t packq4(float4 f, float sc) {
  uint32_t b0 = (uint32_t)(uint8_t)(int8_t)rneclamp(f.x * sc);
  uint32_t b1 = (uint32_t)(uint8_t)(int8_t)rneclamp(f.y * sc);
  uint32_t b2 = (uint32_t)(uint8_t)(int8_t)rneclamp(f.z * sc);
  uint32_t b3 = (uint32_t)(uint8_t)(int8_t)rneclamp(f.w * sc);
  return b0 | (b1 << 8) | (b2 << 16) | (b3 << 24);
}

// ---------------------------------------------------------------------------
// prep: quantize W (I x 3H) and R (H x 3H) to int8 in k-chunk-transposed
// layout:  Xq[((k>>4)*768 + j)*16 + (k&15)]  -> uint4 #kk of column j at
// ((uint4*)Xq)[kk*768 + j]  (coalesced loads for consecutive j).
// ---------------------------------------------------------------------------
__global__ void prep_kernel(const float* __restrict__ W, const float* __restrict__ R,
                            const float* __restrict__ bx, const float* __restrict__ br,
                            int8_t* __restrict__ Wq, int8_t* __restrict__ Rq,
                            int8_t* __restrict__ bx8, int8_t* __restrict__ br8) {
  const int NW = IDIM * N3H; // 196608
  int idx = blockIdx.x * 256 + threadIdx.x;
  if (idx < NW) {
    int k = idx / N3H, j = idx % N3H;
    Wq[((size_t)(k >> 4) * N3H + j) * 16 + (k & 15)] = (int8_t)rneclamp(W[idx] * 256.0f);
  } else if (idx < 2 * NW) {
    int i2 = idx - NW;
    int k = i2 / N3H, j = i2 % N3H;
    Rq[((size_t)(k >> 4) * N3H + j) * 16 + (k & 15)] = (int8_t)rneclamp(R[i2] * 256.0f);
  } else if (idx < 2 * NW + N3H) {
    int i2 = idx - 2 * NW;
    bx8[i2] = (int8_t)rneclamp(bx[i2] * 256.0f);
  } else if (idx < 2 * NW + 2 * N3H) {
    int i2 = idx - 2 * NW - N3H;
    br8[i2] = (int8_t)rneclamp(br[i2] * 256.0f);
  }
}

// ---------------------------------------------------------------------------
// gemm_wx: Wx_q[b][t][j] = clamp(rne( (fq(x) . Wq col j) / 256 ))  (int8)
// one block per t (64 rows), 768 threads = one per output column.
// ---------------------------------------------------------------------------
__global__ __launch_bounds__(768, 1) void gemm_wx_kernel(
    const float* __restrict__ x, const int8_t* __restrict__ Wq,
    int8_t* __restrict__ WxQ8) {
  const int t = blockIdx.x;   // 0..511
  const int j = threadIdx.x;  // 0..767

  __shared__ uint4 xq4[64 * 16];   // 64 rows x 256 int8 = 16KB
  uint32_t* xq = (uint32_t*)xq4;

  // weights for column j: 16 uint4, coalesced from transposed layout
  uint4 w[16];
  const uint4* wp = (const uint4*)Wq;
  #pragma unroll
  for (int kk = 0; kk < 16; ++kk) w[kk] = wp[kk * N3H + j];

  // stage + quantize x tile: rows = x[t][b][:], b=0..63
  const float4* xg = (const float4*)(x) + (size_t)t * 4096;
  for (int i = j; i < 4096; i += 768) {
    float4 f = xg[i];
    xq[i] = packq4(f, 128.0f);
  }
  __syncthreads();

  for (int r = 0; r < 64; ++r) {
    int s = 0;
    #pragma unroll
    for (int kk = 0; kk < 16; ++kk) {
      uint4 hv = xq4[r * 16 + kk];
      s = DOT4(hv.x, w[kk].x, s);
      s = DOT4(hv.y, w[kk].y, s);
      s = DOT4(hv.z, w[kk].z, s);
      s = DOT4(hv.w, w[kk].w, s);
    }
    int q = rneclamp((float)s * (1.0f / 256.0f));
    WxQ8[((size_t)r * T_STEPS + t) * N3H + j] = (int8_t)q;
  }
}

// ---------------------------------------------------------------------------
// gru_rec2: one block per batch element; 256 threads, thread j owns h[j]
// and its full gate triple (columns j, j+256, j+512 of R).
// ---------------------------------------------------------------------------
__global__ __launch_bounds__(256, 1) void gru_rec2_kernel(
    const float* __restrict__ h0, const int8_t* __restrict__ Rq,
    const int8_t* __restrict__ bx8, const int8_t* __restrict__ br8,
    const int8_t* __restrict__ WxQ8, float* __restrict__ out) {
  const int b = blockIdx.x;     // batch element
  const int j = threadIdx.x;    // 0..255
  const int lane = j & 63;

  __shared__ uint32_t hq[2][64];    // double-buffered int8 h (256 B each)
  __shared__ int8_t lutS[256];
  __shared__ int8_t lutT[256];

  // R columns j, j+256, j+512 in registers: 3 x 16 uint4 = 192 VGPRs
  uint4 wz[16], wr[16], wg[16];
  const uint4* rp = (const uint4*)Rq;
  #pragma unroll
  for (int kk = 0; kk < 16; ++kk) {
    wz[kk] = rp[kk * N3H + j];
    wr[kk] = rp[kk * N3H + 256 + j];
    wg[kk] = rp[kk * N3H + 512 + j];
  }
  const int bz  = (int)bx8[j];
  const int brg = (int)bx8[j + 256];
  const int bg  = (int)bx8[j + 512];
  const int vbz = (int)br8[j];
  const int vbr = (int)br8[j + 256];
  const int vbg = (int)br8[j + 512];

  // LUTs in f64 (inputs are fq-clamped to k/128, k in [-128,127])
  {
    double a = ((double)j - 128.0) / 128.0;
    lutS[j] = (int8_t)min(127, max(-128, (int)rint(128.0 / (1.0 + exp(-a)))));
    lutT[j] = (int8_t)min(127, max(-128, (int)rint(128.0 * tanh(a))));
  }
  float hf = h0[b * HDIM + j];
  ((int8_t*)&hq[0][0])[j] = (int8_t)rneclamp(hf * 128.0f);
  __syncthreads();

  const int8_t* wxp = WxQ8 + (size_t)b * T_STEPS * N3H + j;
  float* outp = out + (size_t)b * HDIM + j;

  // prefetch Wx for t=0
  int wxz = (int)wxp[0];
  int wxr = (int)wxp[256];
  int wxg = (int)wxp[512];

  for (int t = 0; t < T_STEPS; ++t) {
    const int cur = t & 1, nxt = cur ^ 1;
    // issue next step's Wx loads early (used only after the barrier)
    int nz = 0, nr = 0, ng = 0;
    if (t + 1 < T_STEPS) {
      const int8_t* p = wxp + (size_t)(t + 1) * N3H;
      nz = (int)p[0]; nr = (int)p[256]; ng = (int)p[512];
    }

    // ---- GEMV: h broadcast via readlane -> SGPR, dot4 against reg weights
    uint32_t hw = hq[cur][lane];      // one ds_read_b32 per wave
    int sz = 0, sr = 0, sg = 0;
    #pragma unroll
    for (int c = 0; c < 64; ++c) {
      int hc = __builtin_amdgcn_readlane((int)hw, c);
      sz = DOT4(hc, CHUNK(wz, c), sz);
      sr = DOT4(hc, CHUNK(wr, c), sr);
      sg = DOT4(hc, CHUNK(wg, c), sg);
    }
    // Rh = fq(hq@Rq,7): rne(s/256); v = fq(Rh+brq,7): rne((2Rh+br)/2)
    int Rz = rneclamp((float)sz * (1.0f / 256.0f));
    int Rr = rneclamp((float)sr * (1.0f / 256.0f));
    int Rg = rneclamp((float)sg * (1.0f / 256.0f));
    int vz = rneclamp((float)(2 * Rz + vbz) * 0.5f);
    int vr = rneclamp((float)(2 * Rr + vbr) * 0.5f);
    int vg = rneclamp((float)(2 * Rg + vbg) * 0.5f);

    // ---- gates (all local to this thread)
    int az = rneclamp((float)(2 * wxz + bz + 2 * vz) * 0.5f);
    int zi = (int)lutS[az + 128];
    int ar = rneclamp((float)(2 * wxr + brg + 2 * vr) * 0.5f);
    int ri = (int)lutS[ar + 128];
    int rrh = rneclamp((float)(ri * vg) * (1.0f / 128.0f));
    int ag = rneclamp((float)(2 * wxg + bg + 2 * rrh) * 0.5f);
    int gi = (int)lutT[ag + 128];
    int oldi = rneclamp((float)zi * hf);
    int newi = rneclamp((float)((128 - zi) * gi) * (1.0f / 128.0f));
    int hi = oldi + newi;              // integer, units 1/128
    hf = (float)hi * (1.0f / 128.0f);
    outp[(size_t)t * BATCH * HDIM] = hf;   // out[t][b][j]
    ((int8_t*)&hq[nxt][0])[j] = (int8_t)min(127, max(-128, hi));
    __syncthreads();

    wxz = nz; wxr = nr; wxg = ng;
  }
}

// ---------------------------------------------------------------------------
extern "C" void kernel_launch(void* const* d_in, const int* in_sizes, int n_in,
                              void* d_out, int out_size, void* d_ws, size_t ws_size,
                              hipStream_t stream) {
  const float* x  = (const float*)d_in[0];   // (T,B,I)
  const float* h0 = (const float*)d_in[1];   // (B,H)
  const float* W  = (const float*)d_in[2];   // (I,3H)
  const float* R  = (const float*)d_in[3];   // (H,3H)
  const float* bx = (const float*)d_in[4];   // (3H,)
  const float* br = (const float*)d_in[5];   // (3H,)
  float* out = (float*)d_out;                // (T,B,H)

  // workspace layout
  const size_t NW = (size_t)IDIM * N3H;          // 196608
  int8_t* Wq  = (int8_t*)d_ws;                   // 196608
  int8_t* Rq  = Wq + NW;                         // 196608
  int8_t* bx8 = Rq + NW;                         // 768
  int8_t* br8 = bx8 + N3H;                       // 768
  int8_t* WxQ8 = br8 + N3H;                      // 64*512*768 = 25165824

  {
    int total = (int)(2 * NW + 2 * N3H);
    int blocks = (total + 255) / 256;
    prep_kernel<<<blocks, 256, 0, stream>>>(W, R, bx, br, Wq, Rq, bx8, br8);
  }
  gemm_wx_kernel<<<T_STEPS, 768, 0, stream>>>(x, Wq, WxQ8);
  gru_rec2_kernel<<<BATCH, 256, 0, stream>>>(h0, Rq, bx8, br8, WxQ8, out);
}